// Round 6
// baseline (161.801 us; speedup 1.0000x reference)
//
#include <hip/hip_runtime.h>
#include <hip/hip_bf16.h>

// Problem constants (fixed by reference)
#define BATCH 2
#define NPTS  8192
#define BN    (BATCH * NPTS)   // 16384
#define KNN   16
#define HEADS 4
#define HD    128              // HEADS*32
#define CIN   64
#define COUT  128
#define WCOLS 384              // [WqA1 | WkA1 | Wv] columns

using short8  = __attribute__((ext_vector_type(8))) short;
using float4v = __attribute__((ext_vector_type(4))) float;

static __device__ __forceinline__ unsigned short f2bf(float x) {
    unsigned u = __float_as_uint(x);
    u += 0x7fffu + ((u >> 16) & 1u);          // round-to-nearest-even
    return (unsigned short)(u >> 16);
}
static __device__ __forceinline__ float bf_lo(unsigned u) { return __uint_as_float(u << 16); }
static __device__ __forceinline__ float bf_hi(unsigned u) { return __uint_as_float(u & 0xffff0000u); }
static __device__ __forceinline__ unsigned pack2(float a, float b) {
    return (unsigned)f2bf(a) | ((unsigned)f2bf(b) << 16);
}

// DPP row ops (row = 16 lanes). row_ror:n ctrl = 0x120+n.
template <int CTRL>
static __device__ __forceinline__ float dpp_mov(float x) {
    return __int_as_float(
        __builtin_amdgcn_update_dpp(0, __float_as_int(x), CTRL, 0xf, 0xf, false));
}
static __device__ __forceinline__ float ror_sum16(float x) {
    x += dpp_mov<0x128>(x);
    x += dpp_mov<0x124>(x);
    x += dpp_mov<0x122>(x);
    x += dpp_mov<0x121>(x);
    return x;
}
static __device__ __forceinline__ float ror_max16(float x) {
    x = fmaxf(x, dpp_mov<0x128>(x));
    x = fmaxf(x, dpp_mov<0x124>(x));
    x = fmaxf(x, dpp_mov<0x122>(x));
    x = fmaxf(x, dpp_mov<0x121>(x));
    return x;
}

// ---------------------------------------------------------------------------
// Kernel P: fold weights, coalesced edition. Lane = output column n so the
// A1[m][n] walk is a 256B coalesced load and W[kk][m] is wave-uniform.
// Wave map (W = global wave id, 648 waves total = 162 blocks x 4):
//   W <384       : WcatT[n][kk] (wave: kk=W/6, n=(W%6)*64+lane)
//   W <384+256   : WoutT[n][kk] = Wout[kk][n]   (linear transpose)
//   W <646       : P2A1[r][j] = (P2@A1)[r][j]
//   W <648       : cvec[j] = b1[j] + (bp2@A1)[j]
// ---------------------------------------------------------------------------
__global__ __launch_bounds__(256) void prep_kernel(
        const float* __restrict__ Wk, const float* __restrict__ Wv,
        const float* __restrict__ Wq, const float* __restrict__ A1,
        const float* __restrict__ b1, const float* __restrict__ P2,
        const float* __restrict__ bp2, const float* __restrict__ Wout,
        unsigned short* __restrict__ WcatT, unsigned short* __restrict__ WoutT,
        float* __restrict__ P2A1, float* __restrict__ cvec) {
    int W = blockIdx.x * 4 + (threadIdx.x >> 6);
    int lane = threadIdx.x & 63;
    if (W < 384) {
        int kk = W / 6, nb = W % 6;
        int n = nb * 64 + lane;
        if (nb < 4) {
            const float* src = (nb < 2 ? Wq : Wk) + kk * HD;
            int jj = n & (HD - 1);
            float acc = 0.f;
            #pragma unroll 8
            for (int m = 0; m < HD; ++m)
                acc += src[m] * A1[m * HD + jj];
            WcatT[n * CIN + kk] = f2bf(acc);
        } else {
            WcatT[n * CIN + kk] = f2bf(Wv[kk * HD + (n - 2 * HD)]);
        }
    } else if (W < 384 + 256) {
        int u = (W - 384) * 64 + lane;        // u = n*128 + kk
        int n = u >> 7, kk = u & 127;
        WoutT[u] = f2bf(Wout[kk * COUT + n]);
    } else if (W < 646) {
        int u = (W - 640) * 64 + lane;        // [0,384)
        int r = u >> 7, j = u & 127;
        const float* src = P2 + r * HD;
        float acc = 0.f;
        #pragma unroll 8
        for (int m = 0; m < HD; ++m)
            acc += src[m] * A1[m * HD + j];
        P2A1[u] = acc;
    } else {
        int j = (W - 646) * 64 + lane;        // [0,128)
        float acc = b1[j];
        #pragma unroll 8
        for (int m = 0; m < HD; ++m)
            acc += bp2[m] * A1[m * HD + j];
        cvec[j] = acc;
    }
}

// ---------------------------------------------------------------------------
// Kernel A (MFMA): QKVb[16384][384] bf16 = bf16(F) @ Wcat (+cvec on n<128).
// 64 rows/block. Waves split the 384 cols: wave w owns n0=w*96 (6 n-tiles).
// A (F->bf16) staged in LDS (stride 88 shorts); B-frags loaded straight from
// global WcatT[n][k] (fragment-ready, L2-resident, 2KB/wave).
// Swapped operands: mfma(A_op=b_frag(n), B_op=a_frag(m)) -> D[row=n][col=m];
// lane holds 4 consecutive n at point-row ml -> packed uint2 stores.
// ---------------------------------------------------------------------------
#define AK 88
__global__ __launch_bounds__(256) void qkv_kernel(const float* __restrict__ F,
                                                  const unsigned short* __restrict__ WcatT,
                                                  const float* __restrict__ cvec,
                                                  unsigned short* __restrict__ QKVb) {
    __shared__ unsigned short Af[64 * AK];     // 11.3 KB
    int p0 = blockIdx.x * 64;
    int t = threadIdx.x;

    // stage A: 64x64 fp32 -> bf16, coalesced
    #pragma unroll
    for (int i = 0; i < 4; ++i) {
        int v = t + i * 256;
        int row = v >> 4, c4 = (v & 15) * 4;
        float4 fa = *(const float4*)(F + (p0 + row) * CIN + c4);
        *(uint2*)(&Af[row * AK + c4]) = make_uint2(pack2(fa.x, fa.y), pack2(fa.z, fa.w));
    }
    __syncthreads();

    int w = t >> 6, l = t & 63;
    int ml = l & 15, quad = l >> 4;
    int n0 = w * 96;

    // B-frags from global: 6 n-tiles x 2 k-halves
    short8 b[6][2];
    #pragma unroll
    for (int j = 0; j < 6; ++j) {
        int n = n0 + j * 16 + ml;
        b[j][0] = *(const short8*)(WcatT + n * CIN + quad * 8);
        b[j][1] = *(const short8*)(WcatT + n * CIN + 32 + quad * 8);
    }
    // A-frags from LDS: 4 m-tiles x 2 k-halves
    short8 a[4][2];
    #pragma unroll
    for (int mt = 0; mt < 4; ++mt) {
        a[mt][0] = *(const short8*)(&Af[(mt * 16 + ml) * AK + quad * 8]);
        a[mt][1] = *(const short8*)(&Af[(mt * 16 + ml) * AK + 32 + quad * 8]);
    }

    #pragma unroll
    for (int j = 0; j < 6; ++j) {
        #pragma unroll
        for (int mt = 0; mt < 4; ++mt) {
            float4v acc = {0.f, 0.f, 0.f, 0.f};
            acc = __builtin_amdgcn_mfma_f32_16x16x32_bf16(b[j][0], a[mt][0], acc, 0, 0, 0);
            acc = __builtin_amdgcn_mfma_f32_16x16x32_bf16(b[j][1], a[mt][1], acc, 0, 0, 0);
            int nc = n0 + j * 16 + quad * 4;         // 4 consecutive n from here
            float c0 = 0.f, c1 = 0.f, c2 = 0.f, c3 = 0.f;
            if (nc < HD) {                            // q-slice gets cvec
                float4 cv = *(const float4*)(cvec + nc);
                c0 = cv.x; c1 = cv.y; c2 = cv.z; c3 = cv.w;
            }
            int row = p0 + mt * 16 + ml;
            *(uint2*)(QKVb + row * WCOLS + nc) =
                make_uint2(pack2(acc[0] + c0, acc[1] + c1),
                           pack2(acc[2] + c2, acc[3] + c3));
        }
    }
}

// ---------------------------------------------------------------------------
// Kernel B: per-point attention (DPP; unchanged from R5).
// ---------------------------------------------------------------------------
__global__ __launch_bounds__(256) void attn_kernel(
        const float* __restrict__ xyzs, const int* __restrict__ kg,
        const unsigned short* __restrict__ QKVb,
        const float* __restrict__ P1, const float* __restrict__ bp1,
        const float* __restrict__ P2, const float* __restrict__ bp2,
        const float* __restrict__ P2A1,
        const float* __restrict__ A2, const float* __restrict__ b2,
        unsigned short* __restrict__ FUSEDb) {
    int p = blockIdx.x;
    int b = p >> 13;              // p / NPTS
    int t = threadIdx.x;
    int g = t >> 4, k = t & 15, c0 = g * 8;
    int w = t >> 6;
    int lane = t & 63;

    __shared__ float4 A2s[HD];
    __shared__ float4 lgp[4][16];
    __shared__ float4 hs16[16];
    __shared__ float  ats[64];
    __shared__ float4 hbf[4];

    if (t < HD) A2s[t] = *(const float4*)(A2 + t * 4);

    int idx = kg[p * KNN + k];
    int q = b * NPTS + idx;

    float r0 = xyzs[p*3+0] - xyzs[q*3+0];
    float r1 = xyzs[p*3+1] - xyzs[q*3+1];
    float r2 = xyzs[p*3+2] - xyzs[q*3+2];
    float h0 = fmaxf(r0*P1[0] + r1*P1[3] + r2*P1[6] + bp1[0], 0.f);
    float h1 = fmaxf(r0*P1[1] + r1*P1[4] + r2*P1[7] + bp1[1], 0.f);
    float h2 = fmaxf(r0*P1[2] + r1*P1[5] + r2*P1[8] + bp1[2], 0.f);
    if (g == 0) hs16[k] = make_float4(h0, h1, h2, 0.f);

    uint4 qu = *(const uint4*)(QKVb + p * WCOLS + c0);
    uint4 ku = *(const uint4*)(QKVb + q * WCOLS + HD + c0);
    uint4 vu = *(const uint4*)(QKVb + q * WCOLS + 2 * HD + c0);

    float qz[8] = { bf_lo(qu.x), bf_hi(qu.x), bf_lo(qu.y), bf_hi(qu.y),
                    bf_lo(qu.z), bf_hi(qu.z), bf_lo(qu.w), bf_hi(qu.w) };
    float kr[8] = { bf_lo(ku.x), bf_hi(ku.x), bf_lo(ku.y), bf_hi(ku.y),
                    bf_lo(ku.z), bf_hi(ku.z), bf_lo(ku.w), bf_hi(ku.w) };

    float wa0[8], wa1[8], wa2[8];
    *(float4*)(wa0)     = *(const float4*)(P2A1 + 0*HD + c0);
    *(float4*)(wa0 + 4) = *(const float4*)(P2A1 + 0*HD + c0 + 4);
    *(float4*)(wa1)     = *(const float4*)(P2A1 + 1*HD + c0);
    *(float4*)(wa1 + 4) = *(const float4*)(P2A1 + 1*HD + c0 + 4);
    *(float4*)(wa2)     = *(const float4*)(P2A1 + 2*HD + c0);
    *(float4*)(wa2 + 4) = *(const float4*)(P2A1 + 2*HD + c0 + 4);

    __syncthreads();   // A2s / hs16 visible

    float pl0 = 0.f, pl1 = 0.f, pl2 = 0.f, pl3 = 0.f;
    #pragma unroll
    for (int j = 0; j < 8; ++j) {
        float z = fmaxf(qz[j] - kr[j] + h0*wa0[j] + h1*wa1[j] + h2*wa2[j], 0.f);
        float4 ar = A2s[c0 + j];
        pl0 += z * ar.x; pl1 += z * ar.y; pl2 += z * ar.z; pl3 += z * ar.w;
    }
    pl0 += __shfl_xor(pl0, 16, 64); pl0 += __shfl_xor(pl0, 32, 64);
    pl1 += __shfl_xor(pl1, 16, 64); pl1 += __shfl_xor(pl1, 32, 64);
    pl2 += __shfl_xor(pl2, 16, 64); pl2 += __shfl_xor(pl2, 32, 64);
    pl3 += __shfl_xor(pl3, 16, 64); pl3 += __shfl_xor(pl3, 32, 64);
    if (lane < 16) lgp[w][lane] = make_float4(pl0, pl1, pl2, pl3);
    __syncthreads();

    if (t < 64) {
        int hh = t >> 4, kk = t & 15;
        const float* lp = (const float*)lgp;
        float lgt = b2[hh] + lp[0*64 + kk*4 + hh] + lp[1*64 + kk*4 + hh]
                           + lp[2*64 + kk*4 + hh] + lp[3*64 + kk*4 + hh];
        float m = ror_max16(lgt);
        float e = __expf(lgt - m);
        float s = ror_sum16(e);
        float a = e / s;
        ats[t] = a;
        float4 hv = hs16[kk];
        float hb0 = ror_sum16(a * hv.x);
        float hb1 = ror_sum16(a * hv.y);
        float hb2 = ror_sum16(a * hv.z);
        if (kk == 0) hbf[hh] = make_float4(hb0, hb1, hb2, 0.f);
    }
    __syncthreads();

    float a = ats[w * 16 + k];
    float vr[8] = { bf_lo(vu.x), bf_hi(vu.x), bf_lo(vu.y), bf_hi(vu.y),
                    bf_lo(vu.z), bf_hi(vu.z), bf_lo(vu.w), bf_hi(vu.w) };
    float wv[8];
    #pragma unroll
    for (int j = 0; j < 8; ++j) wv[j] = ror_sum16(a * vr[j]);

    if (k == 0) {
        float4 hb = hbf[w];
        float q0[8], q1[8], q2[8], bpv[8];
        *(float4*)(q0)     = *(const float4*)(P2 + 0*HD + c0);
        *(float4*)(q0 + 4) = *(const float4*)(P2 + 0*HD + c0 + 4);
        *(float4*)(q1)     = *(const float4*)(P2 + 1*HD + c0);
        *(float4*)(q1 + 4) = *(const float4*)(P2 + 1*HD + c0 + 4);
        *(float4*)(q2)     = *(const float4*)(P2 + 2*HD + c0);
        *(float4*)(q2 + 4) = *(const float4*)(P2 + 2*HD + c0 + 4);
        *(float4*)(bpv)     = *(const float4*)(bp2 + c0);
        *(float4*)(bpv + 4) = *(const float4*)(bp2 + c0 + 4);
        float f[8];
        #pragma unroll
        for (int j = 0; j < 8; ++j)
            f[j] = wv[j] + hb.x*q0[j] + hb.y*q1[j] + hb.z*q2[j] + bpv[j];
        uint4 fu;
        fu.x = pack2(f[0], f[1]); fu.y = pack2(f[2], f[3]);
        fu.z = pack2(f[4], f[5]); fu.w = pack2(f[6], f[7]);
        *(uint4*)(FUSEDb + p * HD + c0) = fu;
    }
}

// ---------------------------------------------------------------------------
// Kernel C (MFMA): out[16384][128] = FUSEDb @ Wout + bout (fp32 out).
// Same structure as qkv: waves split n (32 each), B-frags from global,
// swapped operands -> float4 stores.
// ---------------------------------------------------------------------------
#define OK2 144
__global__ __launch_bounds__(256) void out_kernel(const unsigned short* __restrict__ FUSEDb,
                                                  const unsigned short* __restrict__ WoutT,
                                                  const float* __restrict__ bout,
                                                  float* __restrict__ out) {
    __shared__ unsigned short Af[64 * OK2];    // 18.4 KB
    int p0 = blockIdx.x * 64;
    int t = threadIdx.x;

    #pragma unroll
    for (int i = 0; i < 4; ++i) {              // stage A: 64 x 128 bf16
        int v = t + i * 256;
        int row = v >> 4, c8 = (v & 15) * 8;
        *(uint4*)(&Af[row * OK2 + c8]) = *(const uint4*)(FUSEDb + (p0 + row) * HD + c8);
    }
    __syncthreads();

    int w = t >> 6, l = t & 63;
    int ml = l & 15, quad = l >> 4;
    int n0 = w * 32;

    short8 b[2][4];
    #pragma unroll
    for (int j = 0; j < 2; ++j) {
        int n = n0 + j * 16 + ml;
        #pragma unroll
        for (int ks = 0; ks < 4; ++ks)
            b[j][ks] = *(const short8*)(WoutT + n * HD + ks * 32 + quad * 8);
    }
    short8 a[4][4];
    #pragma unroll
    for (int mt = 0; mt < 4; ++mt)
        #pragma unroll
        for (int ks = 0; ks < 4; ++ks)
            a[mt][ks] = *(const short8*)(&Af[(mt * 16 + ml) * OK2 + ks * 32 + quad * 8]);

    #pragma unroll
    for (int j = 0; j < 2; ++j) {
        int nc = n0 + j * 16 + quad * 4;
        float4 bo = *(const float4*)(bout + nc);
        #pragma unroll
        for (int mt = 0; mt < 4; ++mt) {
            float4v acc = {0.f, 0.f, 0.f, 0.f};
            #pragma unroll
            for (int ks = 0; ks < 4; ++ks)
                acc = __builtin_amdgcn_mfma_f32_16x16x32_bf16(b[j][ks], a[mt][ks], acc, 0, 0, 0);
            int row = p0 + mt * 16 + ml;
            *(float4*)(out + row * COUT + nc) =
                make_float4(acc[0] + bo.x, acc[1] + bo.y, acc[2] + bo.z, acc[3] + bo.w);
        }
    }
}

// ---------------------------------------------------------------------------
extern "C" void kernel_launch(void* const* d_in, const int* in_sizes, int n_in,
                              void* d_out, int out_size, void* d_ws, size_t ws_size,
                              hipStream_t stream) {
    const float* xyzs = (const float*)d_in[0];
    const float* feat = (const float*)d_in[1];
    const int*   kg   = (const int*)  d_in[2];
    const float* Wk   = (const float*)d_in[3];
    const float* Wv   = (const float*)d_in[4];
    const float* Wq   = (const float*)d_in[5];
    const float* A1   = (const float*)d_in[6];
    const float* b1   = (const float*)d_in[7];
    const float* A2   = (const float*)d_in[8];
    const float* b2   = (const float*)d_in[9];
    const float* P1   = (const float*)d_in[10];
    const float* bp1  = (const float*)d_in[11];
    const float* P2   = (const float*)d_in[12];
    const float* bp2  = (const float*)d_in[13];
    const float* Wout = (const float*)d_in[14];
    const float* bout = (const float*)d_in[15];
    float* out = (float*)d_out;

    float* ws = (float*)d_ws;
    float* cvec = ws;                               // 128 fp32
    float* P2A1 = ws + 128;                         // 384 fp32
    unsigned short* QKVb  = (unsigned short*)(ws + 512);         // BN*384 bf16 (12.6 MB)
    unsigned short* FUSEDb = QKVb + (size_t)BN * WCOLS;          // BN*128 bf16 (4 MB)
    unsigned short* WcatT = FUSEDb + (size_t)BN * HD;            // 384*64 bf16
    unsigned short* WoutT = WcatT + WCOLS * CIN;                 // 128*128 bf16

    prep_kernel<<<162, 256, 0, stream>>>(
        Wk, Wv, Wq, A1, b1, P2, bp2, Wout, WcatT, WoutT, P2A1, cvec);

    qkv_kernel<<<BN / 64, 256, 0, stream>>>(feat, WcatT, cvec, QKVb);

    attn_kernel<<<BN, 256, 0, stream>>>(
        xyzs, kg, QKVb, P1, bp1, P2, bp2, P2A1, A2, b2, FUSEDb);

    out_kernel<<<BN / 64, 256, 0, stream>>>(FUSEDb, WoutT, bout, out);
}

// Round 8
// 161.750 us; speedup vs baseline: 1.0003x; 1.0003x over previous
//
#include <hip/hip_runtime.h>
#include <hip/hip_bf16.h>
#include <hip/hip_cooperative_groups.h>

namespace cg = cooperative_groups;

// Problem constants (fixed by reference)
#define BATCH 2
#define NPTS  8192
#define BN    (BATCH * NPTS)   // 16384
#define KNN   16
#define HEADS 4
#define HD    128              // HEADS*32
#define CIN   64
#define COUT  128
#define WCOLS 384              // [WqA1 | WkA1 | Wv] columns

using short8  = __attribute__((ext_vector_type(8))) short;
using float4v = __attribute__((ext_vector_type(4))) float;

static __device__ __forceinline__ unsigned short f2bf(float x) {
    unsigned u = __float_as_uint(x);
    u += 0x7fffu + ((u >> 16) & 1u);          // round-to-nearest-even
    return (unsigned short)(u >> 16);
}
static __device__ __forceinline__ float bf_lo(unsigned u) { return __uint_as_float(u << 16); }
static __device__ __forceinline__ float bf_hi(unsigned u) { return __uint_as_float(u & 0xffff0000u); }
static __device__ __forceinline__ unsigned pack2(float a, float b) {
    return (unsigned)f2bf(a) | ((unsigned)f2bf(b) << 16);
}

// DPP row ops (row = 16 lanes). row_ror:n ctrl = 0x120+n.
template <int CTRL>
static __device__ __forceinline__ float dpp_mov(float x) {
    return __int_as_float(
        __builtin_amdgcn_update_dpp(0, __float_as_int(x), CTRL, 0xf, 0xf, false));
}
static __device__ __forceinline__ float ror_sum16(float x) {
    x += dpp_mov<0x128>(x);
    x += dpp_mov<0x124>(x);
    x += dpp_mov<0x122>(x);
    x += dpp_mov<0x121>(x);
    return x;
}
static __device__ __forceinline__ float ror_max16(float x) {
    x = fmaxf(x, dpp_mov<0x128>(x));
    x = fmaxf(x, dpp_mov<0x124>(x));
    x = fmaxf(x, dpp_mov<0x122>(x));
    x = fmaxf(x, dpp_mov<0x121>(x));
    return x;
}

// ===========================================================================
// Cooperative megakernel (preferred path)
// prep -> grid.sync -> qkv -> grid.sync -> attn+out. 1024 x 256, 16 pts/blk.
// ===========================================================================
__global__ __launch_bounds__(256, 4) void mega_kernel(
        const float* __restrict__ xyzs, const float* __restrict__ feat,
        const int* __restrict__ kg,
        const float* __restrict__ Wk, const float* __restrict__ Wv,
        const float* __restrict__ Wq, const float* __restrict__ A1,
        const float* __restrict__ b1, const float* __restrict__ A2,
        const float* __restrict__ b2, const float* __restrict__ P1,
        const float* __restrict__ bp1, const float* __restrict__ P2,
        const float* __restrict__ bp2, const float* __restrict__ Wout,
        const float* __restrict__ bout,
        unsigned short* __restrict__ WcatT, unsigned short* __restrict__ WoutT,
        float* __restrict__ P2A1, float* __restrict__ cvec,
        unsigned short* __restrict__ QKVb, float* __restrict__ out) {
    cg::grid_group grid = cg::this_grid();
    int t = threadIdx.x;
    int bid = blockIdx.x;
    int w = t >> 6, lane = t & 63;

    __shared__ unsigned short Af[16 * 88];          // 2.8 KB  (qkv A stage)
    __shared__ float4 A2s[HD];                      // 2 KB
    __shared__ float4 lgp[2][4][16];                // 2 KB    (dbuf logits)
    __shared__ float4 hs16[2][16];                  // 512 B
    __shared__ float  ats[2][64];                   // 512 B
    __shared__ float4 hbf[2][4];                    // 128 B
    __shared__ unsigned short fusedLDS[16 * 136];   // 4.3 KB

    // ================= phase P: weight prep (648 waves) =================
    {
        int W = bid * 4 + w;
        if (W < 384) {                      // WcatT[n][kk]
            int kk = W / 6, nb = W % 6;
            int n = nb * 64 + lane;
            if (nb < 4) {
                const float* src = (nb < 2 ? Wq : Wk) + kk * HD;
                int jj = n & (HD - 1);
                float acc = 0.f;
                #pragma unroll 8
                for (int m = 0; m < HD; ++m) acc += src[m] * A1[m * HD + jj];
                WcatT[n * CIN + kk] = f2bf(acc);
            } else {
                WcatT[n * CIN + kk] = f2bf(Wv[kk * HD + (n - 2 * HD)]);
            }
        } else if (W < 640) {               // WoutT[n][kk] = Wout[kk][n]
            int u = (W - 384) * 64 + lane;
            int n = u >> 7, kk = u & 127;
            WoutT[u] = f2bf(Wout[kk * COUT + n]);
        } else if (W < 646) {               // P2A1
            int u = (W - 640) * 64 + lane;
            int r = u >> 7, jj = u & 127;
            const float* src = P2 + r * HD;
            float acc = 0.f;
            #pragma unroll 8
            for (int m = 0; m < HD; ++m) acc += src[m] * A1[m * HD + jj];
            P2A1[u] = acc;
        } else if (W < 648) {               // cvec
            int jj = (W - 646) * 64 + lane;
            float acc = b1[jj];
            #pragma unroll 8
            for (int m = 0; m < HD; ++m) acc += bp2[m] * A1[m * HD + jj];
            cvec[jj] = acc;
        }
    }
    grid.sync();

    // ================= phase Q: QKV GEMM (16-row tile) =================
    int p0 = bid * 16;
    {
        {   // stage A: 16 x 64 fp32 -> bf16 (one float4 per thread)
            int row = t >> 4, c4 = (t & 15) * 4;
            float4 fa = *(const float4*)(feat + (p0 + row) * CIN + c4);
            *(uint2*)(&Af[row * 88 + c4]) =
                make_uint2(pack2(fa.x, fa.y), pack2(fa.z, fa.w));
        }
        __syncthreads();
        int ml = lane & 15, quad = lane >> 4;
        int n0 = w * 96;
        short8 a0 = *(const short8*)(&Af[ml * 88 + quad * 8]);
        short8 a1 = *(const short8*)(&Af[ml * 88 + 32 + quad * 8]);
        #pragma unroll
        for (int j = 0; j < 6; ++j) {
            int n = n0 + j * 16 + ml;
            short8 bf0 = *(const short8*)(WcatT + n * CIN + quad * 8);
            short8 bf1 = *(const short8*)(WcatT + n * CIN + 32 + quad * 8);
            float4v acc = {0.f, 0.f, 0.f, 0.f};
            acc = __builtin_amdgcn_mfma_f32_16x16x32_bf16(bf0, a0, acc, 0, 0, 0);
            acc = __builtin_amdgcn_mfma_f32_16x16x32_bf16(bf1, a1, acc, 0, 0, 0);
            int nc = n0 + j * 16 + quad * 4;
            float c0 = 0.f, c1 = 0.f, c2 = 0.f, c3 = 0.f;
            if (nc < HD) {
                float4 cv = *(const float4*)(cvec + nc);
                c0 = cv.x; c1 = cv.y; c2 = cv.z; c3 = cv.w;
            }
            *(uint2*)(QKVb + (p0 + ml) * WCOLS + nc) =
                make_uint2(pack2(acc[0] + c0, acc[1] + c1),
                           pack2(acc[2] + c2, acc[3] + c3));
        }
    }
    grid.sync();

    // ================= phase A: attention (16 points, prefetched) ========
    {
        int b = p0 >> 13;                 // whole block same batch (16 | 8192)
        int g = t >> 4, k = t & 15, c0g = g * 8;

        if (t < HD) A2s[t] = *(const float4*)(A2 + t * 4);

        float wa0[8], wa1[8], wa2[8];
        *(float4*)(wa0)     = *(const float4*)(P2A1 + 0*HD + c0g);
        *(float4*)(wa0 + 4) = *(const float4*)(P2A1 + 0*HD + c0g + 4);
        *(float4*)(wa1)     = *(const float4*)(P2A1 + 1*HD + c0g);
        *(float4*)(wa1 + 4) = *(const float4*)(P2A1 + 1*HD + c0g + 4);
        *(float4*)(wa2)     = *(const float4*)(P2A1 + 2*HD + c0g);
        *(float4*)(wa2 + 4) = *(const float4*)(P2A1 + 2*HD + c0g + 4);
        __syncthreads();                  // A2s visible

        int p = p0;
        int idx = kg[p * KNN + k];
        int q = b * NPTS + idx;
        float xp0 = xyzs[p*3+0], xp1 = xyzs[p*3+1], xp2 = xyzs[p*3+2];
        float xn0 = xyzs[q*3+0], xn1 = xyzs[q*3+1], xn2 = xyzs[q*3+2];
        uint4 qu = *(const uint4*)(QKVb + p * WCOLS + c0g);
        uint4 ku = *(const uint4*)(QKVb + q * WCOLS + HD + c0g);
        uint4 vu = *(const uint4*)(QKVb + q * WCOLS + 2 * HD + c0g);

        for (int j = 0; j < 16; ++j) {
            int pr = j & 1;
            float r0 = xp0 - xn0, r1 = xp1 - xn1, r2 = xp2 - xn2;
            float h0 = fmaxf(r0*P1[0] + r1*P1[3] + r2*P1[6] + bp1[0], 0.f);
            float h1 = fmaxf(r0*P1[1] + r1*P1[4] + r2*P1[7] + bp1[1], 0.f);
            float h2 = fmaxf(r0*P1[2] + r1*P1[5] + r2*P1[8] + bp1[2], 0.f);
            if (g == 0) hs16[pr][k] = make_float4(h0, h1, h2, 0.f);

            int idxN = 0;
            if (j < 15) idxN = kg[(p + 1) * KNN + k];

            float qz[8] = { bf_lo(qu.x), bf_hi(qu.x), bf_lo(qu.y), bf_hi(qu.y),
                            bf_lo(qu.z), bf_hi(qu.z), bf_lo(qu.w), bf_hi(qu.w) };
            float kr[8] = { bf_lo(ku.x), bf_hi(ku.x), bf_lo(ku.y), bf_hi(ku.y),
                            bf_lo(ku.z), bf_hi(ku.z), bf_lo(ku.w), bf_hi(ku.w) };
            float pl0 = 0.f, pl1 = 0.f, pl2 = 0.f, pl3 = 0.f;
            #pragma unroll
            for (int jj = 0; jj < 8; ++jj) {
                float z = fmaxf(qz[jj] - kr[jj] + h0*wa0[jj] + h1*wa1[jj] + h2*wa2[jj], 0.f);
                float4 ar = A2s[c0g + jj];
                pl0 += z * ar.x; pl1 += z * ar.y; pl2 += z * ar.z; pl3 += z * ar.w;
            }
            pl0 += __shfl_xor(pl0, 16, 64); pl0 += __shfl_xor(pl0, 32, 64);
            pl1 += __shfl_xor(pl1, 16, 64); pl1 += __shfl_xor(pl1, 32, 64);
            pl2 += __shfl_xor(pl2, 16, 64); pl2 += __shfl_xor(pl2, 32, 64);
            pl3 += __shfl_xor(pl3, 16, 64); pl3 += __shfl_xor(pl3, 32, 64);
            if (lane < 16) lgp[pr][w][lane] = make_float4(pl0, pl1, pl2, pl3);
            __syncthreads();              // lgp/hs16 ready

            if (t < 64) {                 // wave-0 softmax + hbar
                int hh = t >> 4, kk = t & 15;
                const float* lp = (const float*)&lgp[pr][0][0];
                float lgt = b2[hh] + lp[0*64 + kk*4 + hh] + lp[1*64 + kk*4 + hh]
                                   + lp[2*64 + kk*4 + hh] + lp[3*64 + kk*4 + hh];
                float m = ror_max16(lgt);
                float e = __expf(lgt - m);
                float s = ror_sum16(e);
                float a = e / s;
                ats[pr][t] = a;
                float4 hv = hs16[pr][kk];
                float hb0 = ror_sum16(a * hv.x);
                float hb1 = ror_sum16(a * hv.y);
                float hb2 = ror_sum16(a * hv.z);
                if (kk == 0) hbf[pr][hh] = make_float4(hb0, hb1, hb2, 0.f);
            }

            uint4 quN, kuN, vuN;
            float xp0N = 0.f, xp1N = 0.f, xp2N = 0.f;
            float xn0N = 0.f, xn1N = 0.f, xn2N = 0.f;
            int qN = b * NPTS + idxN;
            if (j < 15) {
                int pn = p + 1;
                xp0N = xyzs[pn*3+0]; xp1N = xyzs[pn*3+1]; xp2N = xyzs[pn*3+2];
                xn0N = xyzs[qN*3+0]; xn1N = xyzs[qN*3+1]; xn2N = xyzs[qN*3+2];
                quN = *(const uint4*)(QKVb + pn * WCOLS + c0g);
                kuN = *(const uint4*)(QKVb + qN * WCOLS + HD + c0g);
                vuN = *(const uint4*)(QKVb + qN * WCOLS + 2 * HD + c0g);
            }
            __syncthreads();              // ats/hbf ready

            float a = ats[pr][w * 16 + k];
            float vr[8] = { bf_lo(vu.x), bf_hi(vu.x), bf_lo(vu.y), bf_hi(vu.y),
                            bf_lo(vu.z), bf_hi(vu.z), bf_lo(vu.w), bf_hi(vu.w) };
            float wv[8];
            #pragma unroll
            for (int jj = 0; jj < 8; ++jj) wv[jj] = ror_sum16(a * vr[jj]);

            if (k == 0) {
                float4 hb = hbf[pr][w];
                float q0[8], q1[8], q2[8], bpv[8];
                *(float4*)(q0)     = *(const float4*)(P2 + 0*HD + c0g);
                *(float4*)(q0 + 4) = *(const float4*)(P2 + 0*HD + c0g + 4);
                *(float4*)(q1)     = *(const float4*)(P2 + 1*HD + c0g);
                *(float4*)(q1 + 4) = *(const float4*)(P2 + 1*HD + c0g + 4);
                *(float4*)(q2)     = *(const float4*)(P2 + 2*HD + c0g);
                *(float4*)(q2 + 4) = *(const float4*)(P2 + 2*HD + c0g + 4);
                *(float4*)(bpv)     = *(const float4*)(bp2 + c0g);
                *(float4*)(bpv + 4) = *(const float4*)(bp2 + c0g + 4);
                float f[8];
                #pragma unroll
                for (int jj = 0; jj < 8; ++jj)
                    f[jj] = wv[jj] + hb.x*q0[jj] + hb.y*q1[jj] + hb.z*q2[jj] + bpv[jj];
                uint4 fu;
                fu.x = pack2(f[0], f[1]); fu.y = pack2(f[2], f[3]);
                fu.z = pack2(f[4], f[5]); fu.w = pack2(f[6], f[7]);
                *(uint4*)(&fusedLDS[j * 136 + c0g]) = fu;
            }

            p += 1; q = qN;
            qu = quN; ku = kuN; vu = vuN;
            xp0 = xp0N; xp1 = xp1N; xp2 = xp2N;
            xn0 = xn0N; xn1 = xn1N; xn2 = xn2N;
        }
        __syncthreads();                  // fusedLDS complete

        // ============= phase O: out GEMM for this block's 16 rows =========
        int ml = lane & 15, quad = lane >> 4;
        short8 afr[4];
        #pragma unroll
        for (int ks = 0; ks < 4; ++ks)
            afr[ks] = *(const short8*)(&fusedLDS[ml * 136 + ks * 32 + quad * 8]);
        int n0 = w * 32;
        #pragma unroll
        for (int jn = 0; jn < 2; ++jn) {
            int n = n0 + jn * 16 + ml;
            float4v acc = {0.f, 0.f, 0.f, 0.f};
            #pragma unroll
            for (int ks = 0; ks < 4; ++ks) {
                short8 bfr = *(const short8*)(WoutT + n * HD + ks * 32 + quad * 8);
                acc = __builtin_amdgcn_mfma_f32_16x16x32_bf16(bfr, afr[ks], acc, 0, 0, 0);
            }
            int nc = n0 + jn * 16 + quad * 4;
            float4 bo = *(const float4*)(bout + nc);
            *(float4*)(out + (p0 + ml) * COUT + nc) =
                make_float4(acc[0] + bo.x, acc[1] + bo.y,
                            acc[2] + bo.z, acc[3] + bo.w);
        }
    }
}

// ===========================================================================
// Fallback path: proven R6 4-kernel pipeline (161.8 us, passing).
// ===========================================================================
__global__ __launch_bounds__(256) void prep_kernel(
        const float* __restrict__ Wk, const float* __restrict__ Wv,
        const float* __restrict__ Wq, const float* __restrict__ A1,
        const float* __restrict__ b1, const float* __restrict__ P2,
        const float* __restrict__ bp2, const float* __restrict__ Wout,
        unsigned short* __restrict__ WcatT, unsigned short* __restrict__ WoutT,
        float* __restrict__ P2A1, float* __restrict__ cvec) {
    int W = blockIdx.x * 4 + (threadIdx.x >> 6);
    int lane = threadIdx.x & 63;
    if (W < 384) {
        int kk = W / 6, nb = W % 6;
        int n = nb * 64 + lane;
        if (nb < 4) {
            const float* src = (nb < 2 ? Wq : Wk) + kk * HD;
            int jj = n & (HD - 1);
            float acc = 0.f;
            #pragma unroll 8
            for (int m = 0; m < HD; ++m) acc += src[m] * A1[m * HD + jj];
            WcatT[n * CIN + kk] = f2bf(acc);
        } else {
            WcatT[n * CIN + kk] = f2bf(Wv[kk * HD + (n - 2 * HD)]);
        }
    } else if (W < 640) {
        int u = (W - 384) * 64 + lane;
        int n = u >> 7, kk = u & 127;
        WoutT[u] = f2bf(Wout[kk * COUT + n]);
    } else if (W < 646) {
        int u = (W - 640) * 64 + lane;
        int r = u >> 7, j = u & 127;
        const float* src = P2 + r * HD;
        float acc = 0.f;
        #pragma unroll 8
        for (int m = 0; m < HD; ++m) acc += src[m] * A1[m * HD + j];
        P2A1[u] = acc;
    } else if (W < 648) {
        int j = (W - 646) * 64 + lane;
        float acc = b1[j];
        #pragma unroll 8
        for (int m = 0; m < HD; ++m) acc += bp2[m] * A1[m * HD + j];
        cvec[j] = acc;
    }
}

#define AK 88
__global__ __launch_bounds__(256) void qkv_kernel(const float* __restrict__ F,
                                                  const unsigned short* __restrict__ WcatT,
                                                  const float* __restrict__ cvec,
                                                  unsigned short* __restrict__ QKVb) {
    __shared__ unsigned short Af[64 * AK];
    int p0 = blockIdx.x * 64;
    int t = threadIdx.x;
    #pragma unroll
    for (int i = 0; i < 4; ++i) {
        int v = t + i * 256;
        int row = v >> 4, c4 = (v & 15) * 4;
        float4 fa = *(const float4*)(F + (p0 + row) * CIN + c4);
        *(uint2*)(&Af[row * AK + c4]) = make_uint2(pack2(fa.x, fa.y), pack2(fa.z, fa.w));
    }
    __syncthreads();
    int w = t >> 6, l = t & 63;
    int ml = l & 15, quad = l >> 4;
    int n0 = w * 96;
    short8 b[6][2];
    #pragma unroll
    for (int j = 0; j < 6; ++j) {
        int n = n0 + j * 16 + ml;
        b[j][0] = *(const short8*)(WcatT + n * CIN + quad * 8);
        b[j][1] = *(const short8*)(WcatT + n * CIN + 32 + quad * 8);
    }
    short8 a[4][2];
    #pragma unroll
    for (int mt = 0; mt < 4; ++mt) {
        a[mt][0] = *(const short8*)(&Af[(mt * 16 + ml) * AK + quad * 8]);
        a[mt][1] = *(const short8*)(&Af[(mt * 16 + ml) * AK + 32 + quad * 8]);
    }
    #pragma unroll
    for (int j = 0; j < 6; ++j) {
        #pragma unroll
        for (int mt = 0; mt < 4; ++mt) {
            float4v acc = {0.f, 0.f, 0.f, 0.f};
            acc = __builtin_amdgcn_mfma_f32_16x16x32_bf16(b[j][0], a[mt][0], acc, 0, 0, 0);
            acc = __builtin_amdgcn_mfma_f32_16x16x32_bf16(b[j][1], a[mt][1], acc, 0, 0, 0);
            int nc = n0 + j * 16 + quad * 4;
            float c0 = 0.f, c1 = 0.f, c2 = 0.f, c3 = 0.f;
            if (nc < HD) {
                float4 cv = *(const float4*)(cvec + nc);
                c0 = cv.x; c1 = cv.y; c2 = cv.z; c3 = cv.w;
            }
            int row = p0 + mt * 16 + ml;
            *(uint2*)(QKVb + row * WCOLS + nc) =
                make_uint2(pack2(acc[0] + c0, acc[1] + c1),
                           pack2(acc[2] + c2, acc[3] + c3));
        }
    }
}

__global__ __launch_bounds__(256) void attn_kernel(
        const float* __restrict__ xyzs, const int* __restrict__ kg,
        const unsigned short* __restrict__ QKVb,
        const float* __restrict__ P1, const float* __restrict__ bp1,
        const float* __restrict__ P2, const float* __restrict__ bp2,
        const float* __restrict__ P2A1,
        const float* __restrict__ A2, const float* __restrict__ b2,
        unsigned short* __restrict__ FUSEDb) {
    int p = blockIdx.x;
    int b = p >> 13;
    int t = threadIdx.x;
    int g = t >> 4, k = t & 15, c0 = g * 8;
    int w = t >> 6;
    int lane = t & 63;

    __shared__ float4 A2s[HD];
    __shared__ float4 lgp[4][16];
    __shared__ float4 hs16[16];
    __shared__ float  ats[64];
    __shared__ float4 hbf[4];

    if (t < HD) A2s[t] = *(const float4*)(A2 + t * 4);

    int idx = kg[p * KNN + k];
    int q = b * NPTS + idx;

    float r0 = xyzs[p*3+0] - xyzs[q*3+0];
    float r1 = xyzs[p*3+1] - xyzs[q*3+1];
    float r2 = xyzs[p*3+2] - xyzs[q*3+2];
    float h0 = fmaxf(r0*P1[0] + r1*P1[3] + r2*P1[6] + bp1[0], 0.f);
    float h1 = fmaxf(r0*P1[1] + r1*P1[4] + r2*P1[7] + bp1[1], 0.f);
    float h2 = fmaxf(r0*P1[2] + r1*P1[5] + r2*P1[8] + bp1[2], 0.f);
    if (g == 0) hs16[k] = make_float4(h0, h1, h2, 0.f);

    uint4 qu = *(const uint4*)(QKVb + p * WCOLS + c0);
    uint4 ku = *(const uint4*)(QKVb + q * WCOLS + HD + c0);
    uint4 vu = *(const uint4*)(QKVb + q * WCOLS + 2 * HD + c0);

    float qz[8] = { bf_lo(qu.x), bf_hi(qu.x), bf_lo(qu.y), bf_hi(qu.y),
                    bf_lo(qu.z), bf_hi(qu.z), bf_lo(qu.w), bf_hi(qu.w) };
    float kr[8] = { bf_lo(ku.x), bf_hi(ku.x), bf_lo(ku.y), bf_hi(ku.y),
                    bf_lo(ku.z), bf_hi(ku.z), bf_lo(ku.w), bf_hi(ku.w) };

    float wa0[8], wa1[8], wa2[8];
    *(float4*)(wa0)     = *(const float4*)(P2A1 + 0*HD + c0);
    *(float4*)(wa0 + 4) = *(const float4*)(P2A1 + 0*HD + c0 + 4);
    *(float4*)(wa1)     = *(const float4*)(P2A1 + 1*HD + c0);
    *(float4*)(wa1 + 4) = *(const float4*)(P2A1 + 1*HD + c0 + 4);
    *(float4*)(wa2)     = *(const float4*)(P2A1 + 2*HD + c0);
    *(float4*)(wa2 + 4) = *(const float4*)(P2A1 + 2*HD + c0 + 4);

    __syncthreads();

    float pl0 = 0.f, pl1 = 0.f, pl2 = 0.f, pl3 = 0.f;
    #pragma unroll
    for (int j = 0; j < 8; ++j) {
        float z = fmaxf(qz[j] - kr[j] + h0*wa0[j] + h1*wa1[j] + h2*wa2[j], 0.f);
        float4 ar = A2s[c0 + j];
        pl0 += z * ar.x; pl1 += z * ar.y; pl2 += z * ar.z; pl3 += z * ar.w;
    }
    pl0 += __shfl_xor(pl0, 16, 64); pl0 += __shfl_xor(pl0, 32, 64);
    pl1 += __shfl_xor(pl1, 16, 64); pl1 += __shfl_xor(pl1, 32, 64);
    pl2 += __shfl_xor(pl2, 16, 64); pl2 += __shfl_xor(pl2, 32, 64);
    pl3 += __shfl_xor(pl3, 16, 64); pl3 += __shfl_xor(pl3, 32, 64);
    if (lane < 16) lgp[w][lane] = make_float4(pl0, pl1, pl2, pl3);
    __syncthreads();

    if (t < 64) {
        int hh = t >> 4, kk = t & 15;
        const float* lp = (const float*)lgp;
        float lgt = b2[hh] + lp[0*64 + kk*4 + hh] + lp[1*64 + kk*4 + hh]
                           + lp[2*64 + kk*4 + hh] + lp[3*64 + kk*4 + hh];
        float m = ror_max16(lgt);
        float e = __expf(lgt - m);
        float s = ror_sum16(e);
        float a = e / s;
        ats[t] = a;
        float4 hv = hs16[kk];
        float hb0 = ror_sum16(a * hv.x);
        float hb1 = ror_sum16(a * hv.y);
        float hb2 = ror_sum16(a * hv.z);
        if (kk == 0) hbf[hh] = make_float4(hb0, hb1, hb2, 0.f);
    }
    __syncthreads();

    float a = ats[w * 16 + k];
    float vr[8] = { bf_lo(vu.x), bf_hi(vu.x), bf_lo(vu.y), bf_hi(vu.y),
                    bf_lo(vu.z), bf_hi(vu.z), bf_lo(vu.w), bf_hi(vu.w) };
    float wv[8];
    #pragma unroll
    for (int j = 0; j < 8; ++j) wv[j] = ror_sum16(a * vr[j]);

    if (k == 0) {
        float4 hb = hbf[w];
        float q0[8], q1[8], q2[8], bpv[8];
        *(float4*)(q0)     = *(const float4*)(P2 + 0*HD + c0);
        *(float4*)(q0 + 4) = *(const float4*)(P2 + 0*HD + c0 + 4);
        *(float4*)(q1)     = *(const float4*)(P2 + 1*HD + c0);
        *(float4*)(q1 + 4) = *(const float4*)(P2 + 1*HD + c0 + 4);
        *(float4*)(q2)     = *(const float4*)(P2 + 2*HD + c0);
        *(float4*)(q2 + 4) = *(const float4*)(P2 + 2*HD + c0 + 4);
        *(float4*)(bpv)     = *(const float4*)(bp2 + c0);
        *(float4*)(bpv + 4) = *(const float4*)(bp2 + c0 + 4);
        float f[8];
        #pragma unroll
        for (int j = 0; j < 8; ++j)
            f[j] = wv[j] + hb.x*q0[j] + hb.y*q1[j] + hb.z*q2[j] + bpv[j];
        uint4 fu;
        fu.x = pack2(f[0], f[1]); fu.y = pack2(f[2], f[3]);
        fu.z = pack2(f[4], f[5]); fu.w = pack2(f[6], f[7]);
        *(uint4*)(FUSEDb + p * HD + c0) = fu;
    }
}

#define OK2 144
__global__ __launch_bounds__(256) void out_kernel(const unsigned short* __restrict__ FUSEDb,
                                                  const unsigned short* __restrict__ WoutT,
                                                  const float* __restrict__ bout,
                                                  float* __restrict__ out) {
    __shared__ unsigned short Af[64 * OK2];
    int p0 = blockIdx.x * 64;
    int t = threadIdx.x;
    #pragma unroll
    for (int i = 0; i < 4; ++i) {
        int v = t + i * 256;
        int row = v >> 4, c8 = (v & 15) * 8;
        *(uint4*)(&Af[row * OK2 + c8]) = *(const uint4*)(FUSEDb + (p0 + row) * HD + c8);
    }
    __syncthreads();
    int w = t >> 6, l = t & 63;
    int ml = l & 15, quad = l >> 4;
    int n0 = w * 32;
    short8 b[2][4];
    #pragma unroll
    for (int j = 0; j < 2; ++j) {
        int n = n0 + j * 16 + ml;
        #pragma unroll
        for (int ks = 0; ks < 4; ++ks)
            b[j][ks] = *(const short8*)(WoutT + n * HD + ks * 32 + quad * 8);
    }
    short8 a[4][4];
    #pragma unroll
    for (int mt = 0; mt < 4; ++mt)
        #pragma unroll
        for (int ks = 0; ks < 4; ++ks)
            a[mt][ks] = *(const short8*)(&Af[(mt * 16 + ml) * OK2 + ks * 32 + quad * 8]);
    #pragma unroll
    for (int j = 0; j < 2; ++j) {
        int nc = n0 + j * 16 + quad * 4;
        float4 bo = *(const float4*)(bout + nc);
        #pragma unroll
        for (int mt = 0; mt < 4; ++mt) {
            float4v acc = {0.f, 0.f, 0.f, 0.f};
            #pragma unroll
            for (int ks = 0; ks < 4; ++ks)
                acc = __builtin_amdgcn_mfma_f32_16x16x32_bf16(b[j][ks], a[mt][ks], acc, 0, 0, 0);
            int row = p0 + mt * 16 + ml;
            *(float4*)(out + row * COUT + nc) =
                make_float4(acc[0] + bo.x, acc[1] + bo.y, acc[2] + bo.z, acc[3] + bo.w);
        }
    }
}

// ---------------------------------------------------------------------------
extern "C" void kernel_launch(void* const* d_in, const int* in_sizes, int n_in,
                              void* d_out, int out_size, void* d_ws, size_t ws_size,
                              hipStream_t stream) {
    const float* xyzs = (const float*)d_in[0];
    const float* feat = (const float*)d_in[1];
    const int*   kg   = (const int*)  d_in[2];
    const float* Wk   = (const float*)d_in[3];
    const float* Wv   = (const float*)d_in[4];
    const float* Wq   = (const float*)d_in[5];
    const float* A1   = (const float*)d_in[6];
    const float* b1   = (const float*)d_in[7];
    const float* A2   = (const float*)d_in[8];
    const float* b2   = (const float*)d_in[9];
    const float* P1   = (const float*)d_in[10];
    const float* bp1  = (const float*)d_in[11];
    const float* P2   = (const float*)d_in[12];
    const float* bp2  = (const float*)d_in[13];
    const float* Wout = (const float*)d_in[14];
    const float* bout = (const float*)d_in[15];
    float* out = (float*)d_out;

    float* ws = (float*)d_ws;
    float* cvec = ws;                                      // 128 fp32
    float* P2A1 = ws + 128;                                // 384 fp32
    unsigned short* QKVb   = (unsigned short*)(ws + 512);  // BN*384 bf16
    unsigned short* WcatT  = QKVb + (size_t)BN * WCOLS;    // 384*64 bf16
    unsigned short* WoutT  = WcatT + WCOLS * CIN;          // 128*128 bf16
    unsigned short* FUSEDb = WoutT + COUT * HD;            // BN*128 bf16 (fallback only)

    // Gate 1: occupancy — cooperative needs all 1024 blocks co-resident.
    int nb = 0;
    bool use_coop =
        (hipOccupancyMaxActiveBlocksPerMultiprocessor(&nb, mega_kernel, 256, 0)
             == hipSuccess) && nb >= 4;

    if (use_coop) {
        void* args[] = {
            (void*)&xyzs, (void*)&feat, (void*)&kg,
            (void*)&Wk, (void*)&Wv, (void*)&Wq, (void*)&A1, (void*)&b1,
            (void*)&A2, (void*)&b2, (void*)&P1, (void*)&bp1, (void*)&P2,
            (void*)&bp2, (void*)&Wout, (void*)&bout,
            (void*)&WcatT, (void*)&WoutT, (void*)&P2A1, (void*)&cvec,
            (void*)&QKVb, (void*)&out
        };
        // Gate 2: the launch itself.
        if (hipLaunchCooperativeKernel((const void*)mega_kernel,
                                       dim3(1024), dim3(256), args, 0, stream)
                != hipSuccess)
            use_coop = false;
    }

    if (!use_coop) {
        prep_kernel<<<162, 256, 0, stream>>>(
            Wk, Wv, Wq, A1, b1, P2, bp2, Wout, WcatT, WoutT, P2A1, cvec);
        qkv_kernel<<<BN / 64, 256, 0, stream>>>(feat, WcatT, cvec, QKVb);
        attn_kernel<<<BN, 256, 0, stream>>>(
            xyzs, kg, QKVb, P1, bp1, P2, bp2, P2A1, A2, b2, FUSEDb);
        out_kernel<<<BN / 64, 256, 0, stream>>>(FUSEDb, WoutT, bout, out);
    }
}